// Round 6
// baseline (1967.205 us; speedup 1.0000x reference)
//
#include <hip/hip_runtime.h>

#define NPG 116          // nodes per graph
#define DEGC 32          // edges per node
#define EPG (NPG * DEGC) // 3712 edges per graph
#define HID 32
#define HID2 64
#define EPS 1e-5f

// A is [116][116] floats, stride 116 (=29 float4, 16B-aligned rows).
// Transposed col tables: stride 124 floats (31 f4) -> balanced LDS banks.
#define TS 124
#define TS4 31
#define WS2 36           // W2T/ysv stride (floats)
#define WS24 9

#define FMA4(acc, a, b)                                                        \
  acc.x += (a).x * (b).x; acc.y += (a).y * (b).y;                              \
  acc.z += (a).z * (b).z; acc.w += (a).w * (b).w;

#define HSUM4(v) (((v).x + (v).y) + ((v).z + (v).w))

#define F4Z make_float4(0.f, 0.f, 0.f, 0.f)

// ---------------------------------------------------------------------------
// ws layout (floats):
//   [0,256)    stats: s1[32] q1[32] s2[64] q2[64]   (memset to 0 each launch)
//   [256, +N)     dinv (computed by conv1, reused by conv2)
//   [.., +32N)    h1  (conv1 output)
//   [.., +64N)    h2  (conv2 output)
//   [.., +32G)    z   (FC1 pre-BN)
// ---------------------------------------------------------------------------

// Fused per-graph: stage x,W1T -> lin1 = x@W1 (reg-tiled 4x2) overlapped with
// A-build atomics -> h1 = A@lin1 (reg-tiled 4x2) + BN1 stat partials.
// 512 thr = 8 waves; LDS ~140KB -> 1 block/CU; VGPR budget fits 128.
__global__ __launch_bounds__(512) void k_conv1(const float* __restrict__ x,
                                               const int* __restrict__ ei,
                                               const float* __restrict__ ew,
                                               const float* __restrict__ W1,
                                               float* __restrict__ h1,
                                               float* __restrict__ dinvg,
                                               float* __restrict__ stats,
                                               int N, int E) {
  __shared__ __align__(16) float A[NPG * NPG];    // adjacency (built phase 2)
  __shared__ __align__(16) float xs[NPG * NPG];   // x tile
  __shared__ __align__(16) float l1T[HID * TS];   // lin1, transposed
  __shared__ __align__(16) float W1T[HID * TS];   // W1, transposed
  __shared__ float degs[NPG];
  __shared__ float ss[HID], qs[HID];
  int g = blockIdx.x, tid = threadIdx.x;
  int nb = g * NPG, e0 = g * EPG;
  const int* rowp = ei;
  const int* colp = ei + E;

  for (int i = tid; i < NPG; i += 512) degs[i] = 1.0f;  // self-loop weight
  if (tid < HID) { ss[tid] = 0.0f; qs[tid] = 0.0f; }
  __syncthreads();

  // phase 1: stage x tile + W1T, zero A, degree atomics
  {
    const float4* xg = (const float4*)(x + (size_t)nb * NPG);
    float4* xs4w = (float4*)xs;
    for (int i = tid; i < NPG * 29; i += 512) xs4w[i] = xg[i];
    for (int i = tid; i < NPG * HID; i += 512) {
      int k = i >> 5, cc = i & 31;
      W1T[cc * TS + k] = W1[i];
    }
    float4* Az = (float4*)A;
    for (int i = tid; i < NPG * 29; i += 512) Az[i] = F4Z;
    for (int e = tid; e < EPG; e += 512) {
      int d = colp[e0 + e] - nb;
      atomicAdd(&degs[d], ew[e0 + e]);
    }
  }
  __syncthreads();
  for (int i = tid; i < NPG; i += 512) {
    float dv = rsqrtf(degs[i]);   // deg >= 1
    degs[i] = dv;
    dinvg[nb + i] = dv;
  }
  __syncthreads();

  const int c = tid & 15, rg = tid >> 4;      // 2 cols (c, c+16), 4 rows
  const int nm = (rg < 20) ? 4 : 3;           // rows rg+32m, m<nm
  const float4* xs4 = (const float4*)xs;
  const float4* A4 = (const float4*)A;
  const float4* w1t = (const float4*)W1T;
  const float4* l1t = (const float4*)l1T;

  // phase 2: A-build atomics (latency) overlap gemm1 (compute)
  for (int e = tid; e < EPG; e += 512) {
    int eg = e0 + e;
    int s = rowp[eg] - nb, d = colp[eg] - nb;
    atomicAdd(&A[d * NPG + s], degs[s] * ew[eg] * degs[d]);
  }
  for (int i = tid; i < NPG; i += 512)
    atomicAdd(&A[i * (NPG + 1)], degs[i] * degs[i]);

  {
    float4 acc[4][2];
#pragma unroll
    for (int m = 0; m < 4; ++m) { acc[m][0] = F4Z; acc[m][1] = F4Z; }
#pragma unroll
    for (int ci = 0; ci < 4; ++ci) {
      const int c0 = ci * 8;
      const int len = (ci < 3) ? 8 : 5;
      float4 wc0[8], wc1[8];
#pragma unroll
      for (int j = 0; j < 8; ++j) {
        if (j < len) {
          wc0[j] = w1t[c * TS4 + c0 + j];
          wc1[j] = w1t[(c + 16) * TS4 + c0 + j];
        }
      }
#pragma unroll
      for (int m = 0; m < 4; ++m) {
        if (m < nm) {
          const float4* pr = xs4 + (rg + 32 * m) * 29 + c0;
#pragma unroll
          for (int j = 0; j < 8; ++j) {
            if (j < len) {
              float4 a = pr[j];
              FMA4(acc[m][0], a, wc0[j]);
              FMA4(acc[m][1], a, wc1[j]);
            }
          }
        }
      }
    }
#pragma unroll
    for (int m = 0; m < 4; ++m) {
      if (m < nm) {
        int r = rg + 32 * m;
        l1T[c * TS + r] = HSUM4(acc[m][0]);
        l1T[(c + 16) * TS + r] = HSUM4(acc[m][1]);
      }
    }
  }
  __syncthreads();  // A built, l1T complete

  // phase 3: h1 = A @ lin1 + stats
  {
    float4 acc[4][2];
#pragma unroll
    for (int m = 0; m < 4; ++m) { acc[m][0] = F4Z; acc[m][1] = F4Z; }
#pragma unroll
    for (int ci = 0; ci < 4; ++ci) {
      const int c0 = ci * 8;
      const int len = (ci < 3) ? 8 : 5;
      float4 wc0[8], wc1[8];
#pragma unroll
      for (int j = 0; j < 8; ++j) {
        if (j < len) {
          wc0[j] = l1t[c * TS4 + c0 + j];
          wc1[j] = l1t[(c + 16) * TS4 + c0 + j];
        }
      }
#pragma unroll
      for (int m = 0; m < 4; ++m) {
        if (m < nm) {
          const float4* pr = A4 + (rg + 32 * m) * 29 + c0;
#pragma unroll
          for (int j = 0; j < 8; ++j) {
            if (j < len) {
              float4 a = pr[j];
              FMA4(acc[m][0], a, wc0[j]);
              FMA4(acc[m][1], a, wc1[j]);
            }
          }
        }
      }
    }
    float s0 = 0.f, q0 = 0.f, s1 = 0.f, q1 = 0.f;
#pragma unroll
    for (int m = 0; m < 4; ++m) {
      if (m < nm) {
        int r = rg + 32 * m;
        float v0 = HSUM4(acc[m][0]);
        float v1 = HSUM4(acc[m][1]);
        float* hrow = h1 + (size_t)(nb + r) * HID;
        hrow[c] = v0;
        hrow[c + 16] = v1;
        s0 += v0; q0 += v0 * v0;
        s1 += v1; q1 += v1 * v1;
      }
    }
    atomicAdd(&ss[c], s0);      atomicAdd(&qs[c], q0);
    atomicAdd(&ss[c + 16], s1); atomicAdd(&qs[c + 16], q1);
  }
  __syncthreads();
  if (tid < HID) {
    atomicAdd(&stats[tid], ss[tid]);
    atomicAdd(&stats[32 + tid], qs[tid]);
  }
}

// Fused per-graph: BN1 coefs -> ys = relu(a1*h1+c1) -> lin2 = ys@W2 (4 rows x
// 2x2 cols) overlapped with A-build -> h2 = A@lin2 (4 rows x 4 cols) + stats.
__global__ __launch_bounds__(512) void k_conv2(const float* __restrict__ h1,
                                               const int* __restrict__ ei,
                                               const float* __restrict__ ew,
                                               const float* __restrict__ W2,
                                               const float* __restrict__ g1,
                                               const float* __restrict__ be1,
                                               const float* __restrict__ stats,
                                               const float* __restrict__ dinvg,
                                               float* __restrict__ h2,
                                               float* __restrict__ stats2,
                                               float invN,
                                               int N, int E) {
  __shared__ __align__(16) float A[NPG * NPG];     // 53.8 KB
  __shared__ __align__(16) float ysv[NPG * WS2];   // 16.7 KB
  __shared__ __align__(16) float l2T[HID2 * TS];   // 31.7 KB
  __shared__ __align__(16) float W2T[HID2 * WS2];  // 9.2 KB
  __shared__ float degs[NPG];
  __shared__ float ss[HID2], qs[HID2];
  __shared__ float a1s[HID], c1s[HID];
  int g = blockIdx.x, tid = threadIdx.x;
  int nb = g * NPG, e0 = g * EPG;
  const int* rowp = ei;
  const int* colp = ei + E;

  if (tid < HID) {
    float m = stats[tid] * invN;
    float v = stats[32 + tid] * invN - m * m;
    float a = g1[tid] * rsqrtf(v + EPS);
    a1s[tid] = a;
    c1s[tid] = be1[tid] - m * a;
  }
  if (tid < HID2) { ss[tid] = 0.0f; qs[tid] = 0.0f; }
  __syncthreads();

  // phase 1: stage ys = relu(a1*h1+c1), W2T, load dinv, zero A
  {
    const float4* hg = (const float4*)(h1 + (size_t)nb * HID);
    float4* ys4w = (float4*)ysv;
    for (int i = tid; i < NPG * 8; i += 512) {
      int r = i >> 3, kc = i & 7, k0 = kc * 4;
      float4 hv = hg[i];
      float4 y;
      y.x = fmaxf(0.f, a1s[k0 + 0] * hv.x + c1s[k0 + 0]);
      y.y = fmaxf(0.f, a1s[k0 + 1] * hv.y + c1s[k0 + 1]);
      y.z = fmaxf(0.f, a1s[k0 + 2] * hv.z + c1s[k0 + 2]);
      y.w = fmaxf(0.f, a1s[k0 + 3] * hv.w + c1s[k0 + 3]);
      ys4w[r * WS24 + kc] = y;
    }
    for (int i = tid; i < HID * HID2; i += 512) {
      int k = i >> 6, cc = i & 63;
      W2T[cc * WS2 + k] = W2[i];
    }
    for (int i = tid; i < NPG; i += 512) degs[i] = dinvg[nb + i];
    float4* Az = (float4*)A;
    for (int i = tid; i < NPG * 29; i += 512) Az[i] = F4Z;
  }
  __syncthreads();

  const int c = tid & 15, rg = tid >> 4;   // 4 cols (c+16t), 4 rows
  const int nm = (rg < 20) ? 4 : 3;
  const float4* ys4 = (const float4*)ysv;
  const float4* w2t = (const float4*)W2T;
  const float4* l2t = (const float4*)l2T;
  const float4* A4 = (const float4*)A;

  // phase 2: A-build atomics overlap gemm2
  for (int e = tid; e < EPG; e += 512) {
    int eg = e0 + e;
    int s = rowp[eg] - nb, d = colp[eg] - nb;
    atomicAdd(&A[d * NPG + s], degs[s] * ew[eg] * degs[d]);
  }
  for (int i = tid; i < NPG; i += 512)
    atomicAdd(&A[i * (NPG + 1)], degs[i] * degs[i]);

#pragma unroll
  for (int tp = 0; tp < 2; ++tp) {
    const int ca = c + 32 * tp;  // cols ca, ca+16
    float4 wc0[8], wc1[8];
#pragma unroll
    for (int j = 0; j < 8; ++j) {
      wc0[j] = w2t[ca * WS24 + j];
      wc1[j] = w2t[(ca + 16) * WS24 + j];
    }
    float4 acc[4][2];
#pragma unroll
    for (int m = 0; m < 4; ++m) { acc[m][0] = F4Z; acc[m][1] = F4Z; }
#pragma unroll
    for (int m = 0; m < 4; ++m) {
      if (m < nm) {
        const float4* pr = ys4 + (rg + 32 * m) * WS24;
#pragma unroll
        for (int j = 0; j < 8; ++j) {
          float4 a = pr[j];
          FMA4(acc[m][0], a, wc0[j]);
          FMA4(acc[m][1], a, wc1[j]);
        }
      }
    }
#pragma unroll
    for (int m = 0; m < 4; ++m) {
      if (m < nm) {
        int r = rg + 32 * m;
        l2T[ca * TS + r] = HSUM4(acc[m][0]);
        l2T[(ca + 16) * TS + r] = HSUM4(acc[m][1]);
      }
    }
  }
  __syncthreads();  // A built, l2T complete

  // phase 3: h2 = A @ lin2 (4 rows x 4 cols, k-chunks of 2 f4) + stats
  {
    float4 acc[4][4];
#pragma unroll
    for (int m = 0; m < 4; ++m)
#pragma unroll
      for (int t = 0; t < 4; ++t) acc[m][t] = F4Z;
#pragma unroll
    for (int ci = 0; ci < 15; ++ci) {
      const int c0 = ci * 2;
      const int len = (ci < 14) ? 2 : 1;
      float4 wc[4][2];
#pragma unroll
      for (int t = 0; t < 4; ++t) {
#pragma unroll
        for (int j = 0; j < 2; ++j) {
          if (j < len) wc[t][j] = l2t[(c + 16 * t) * TS4 + c0 + j];
        }
      }
#pragma unroll
      for (int m = 0; m < 4; ++m) {
        if (m < nm) {
          const float4* pr = A4 + (rg + 32 * m) * 29 + c0;
#pragma unroll
          for (int j = 0; j < 2; ++j) {
            if (j < len) {
              float4 a = pr[j];
#pragma unroll
              for (int t = 0; t < 4; ++t) { FMA4(acc[m][t], a, wc[t][j]); }
            }
          }
        }
      }
    }
    float sA[4] = {0.f, 0.f, 0.f, 0.f}, qA[4] = {0.f, 0.f, 0.f, 0.f};
#pragma unroll
    for (int m = 0; m < 4; ++m) {
      if (m < nm) {
        int r = rg + 32 * m;
        float* hrow = h2 + (size_t)(nb + r) * HID2;
#pragma unroll
        for (int t = 0; t < 4; ++t) {
          float v = HSUM4(acc[m][t]);
          hrow[c + 16 * t] = v;
          sA[t] += v; qA[t] += v * v;
        }
      }
    }
#pragma unroll
    for (int t = 0; t < 4; ++t) {
      atomicAdd(&ss[c + 16 * t], sA[t]);
      atomicAdd(&qs[c + 16 * t], qA[t]);
    }
  }
  __syncthreads();
  if (tid < HID2) {
    atomicAdd(&stats2[tid], ss[tid]);
    atomicAdd(&stats2[64 + tid], qs[tid]);
  }
}

// per-graph BN2 coefs (per-block) + relu, mean/max pool, FC1 -> z
__global__ __launch_bounds__(256) void k_pool(const float* __restrict__ h2,
                                              const float* __restrict__ g2,
                                              const float* __restrict__ be2,
                                              const float* __restrict__ stats2,
                                              const float* __restrict__ Wf1,
                                              float* __restrict__ z,
                                              float invN, int N) {
  __shared__ float4 psum4[256], pmax4[256];
  __shared__ __align__(16) float emb[128];
  __shared__ __align__(16) float a2s[HID2], c2s[HID2];
  int g = blockIdx.x, tid = threadIdx.x;
  if (tid < HID2) {
    float m = stats2[tid] * invN;
    float v = stats2[64 + tid] * invN - m * m;
    float a = g2[tid] * rsqrtf(v + EPS);
    a2s[tid] = a;
    c2s[tid] = be2[tid] - m * a;
  }
  __syncthreads();
  int c4 = tid & 15, rg = tid >> 4;
  float4 av = ((const float4*)a2s)[c4], bv = ((const float4*)c2s)[c4];
  const float4* h4 = (const float4*)h2 + (size_t)g * NPG * 16;
  float4 s = {0.f, 0.f, 0.f, 0.f};
  float4 mx = {-1e30f, -1e30f, -1e30f, -1e30f};
  for (int n = rg; n < NPG; n += 16) {
    float4 v = h4[n * 16 + c4];
    float4 y;
    y.x = fmaxf(0.f, av.x * v.x + bv.x);
    y.y = fmaxf(0.f, av.y * v.y + bv.y);
    y.z = fmaxf(0.f, av.z * v.z + bv.z);
    y.w = fmaxf(0.f, av.w * v.w + bv.w);
    s.x += y.x; s.y += y.y; s.z += y.z; s.w += y.w;
    mx.x = fmaxf(mx.x, y.x); mx.y = fmaxf(mx.y, y.y);
    mx.z = fmaxf(mx.z, y.z); mx.w = fmaxf(mx.w, y.w);
  }
  psum4[rg * 16 + c4] = s;
  pmax4[rg * 16 + c4] = mx;
  __syncthreads();
  if (tid < 16) {
    float4 S = psum4[tid], M = pmax4[tid];
    for (int j = 1; j < 16; ++j) {
      float4 p = psum4[j * 16 + tid], q = pmax4[j * 16 + tid];
      S.x += p.x; S.y += p.y; S.z += p.z; S.w += p.w;
      M.x = fmaxf(M.x, q.x); M.y = fmaxf(M.y, q.y);
      M.z = fmaxf(M.z, q.z); M.w = fmaxf(M.w, q.w);
    }
    const float inv = 1.0f / NPG;
    ((float4*)emb)[tid] = make_float4(S.x * inv, S.y * inv, S.z * inv, S.w * inv);
    ((float4*)emb)[16 + tid] = M;
  }
  __syncthreads();
  if (tid < 32) {
    float acc = 0.0f;
#pragma unroll
    for (int k = 0; k < 128; ++k) acc += emb[k] * Wf1[k * 32 + tid];
    z[g * 32 + tid] = acc;
  }
}

// single block: BNf stats over z (G x 32) -> coeffs -> relu -> FC2 -> out
__global__ __launch_bounds__(256) void k_final(const float* __restrict__ z,
                                               const float* __restrict__ gf,
                                               const float* __restrict__ bef,
                                               const float* __restrict__ Wf2,
                                               const float* __restrict__ bf2,
                                               float* __restrict__ out, int G) {
  __shared__ float ss[32], qs[32], af[32], cf[32];
  __shared__ float w2s[64], b2s[2];
  int tid = threadIdx.x;
  if (tid < 32) { ss[tid] = 0.0f; qs[tid] = 0.0f; }
  if (tid < 64) w2s[tid] = Wf2[tid];
  if (tid < 2) b2s[tid] = bf2[tid];
  __syncthreads();
  const float4* z4 = (const float4*)z;
  int n4 = G * 8;
  float4 s = {0.f, 0.f, 0.f, 0.f}, q = {0.f, 0.f, 0.f, 0.f};
  for (int i = tid; i < n4; i += 256) {
    float4 v = z4[i];
    s.x += v.x; s.y += v.y; s.z += v.z; s.w += v.w;
    q.x += v.x * v.x; q.y += v.y * v.y; q.z += v.z * v.z; q.w += v.w * v.w;
  }
  int cg = (tid & 7) * 4;
  atomicAdd(&ss[cg + 0], s.x); atomicAdd(&ss[cg + 1], s.y);
  atomicAdd(&ss[cg + 2], s.z); atomicAdd(&ss[cg + 3], s.w);
  atomicAdd(&qs[cg + 0], q.x); atomicAdd(&qs[cg + 1], q.y);
  atomicAdd(&qs[cg + 2], q.z); atomicAdd(&qs[cg + 3], q.w);
  __syncthreads();
  if (tid < 32) {
    float invG = 1.0f / G;
    float m = ss[tid] * invG;
    float v = qs[tid] * invG - m * m;
    float a = gf[tid] * rsqrtf(v + EPS);
    af[tid] = a;
    cf[tid] = bef[tid] - m * a;
  }
  __syncthreads();
  for (int g = tid; g < G; g += 256) {
    float o0 = b2s[0], o1 = b2s[1];
    const float4* zr = z4 + g * 8;
#pragma unroll
    for (int kc = 0; kc < 8; ++kc) {
      float4 v = zr[kc];
      int j = 4 * kc;
      float y;
      y = fmaxf(0.f, af[j + 0] * v.x + cf[j + 0]);
      o0 += y * w2s[2 * (j + 0)]; o1 += y * w2s[2 * (j + 0) + 1];
      y = fmaxf(0.f, af[j + 1] * v.y + cf[j + 1]);
      o0 += y * w2s[2 * (j + 1)]; o1 += y * w2s[2 * (j + 1) + 1];
      y = fmaxf(0.f, af[j + 2] * v.z + cf[j + 2]);
      o0 += y * w2s[2 * (j + 2)]; o1 += y * w2s[2 * (j + 2) + 1];
      y = fmaxf(0.f, af[j + 3] * v.w + cf[j + 3]);
      o0 += y * w2s[2 * (j + 3)]; o1 += y * w2s[2 * (j + 3) + 1];
    }
    out[g * 2] = o0;
    out[g * 2 + 1] = o1;
  }
}

extern "C" void kernel_launch(void* const* d_in, const int* in_sizes, int n_in,
                              void* d_out, int out_size, void* d_ws, size_t ws_size,
                              hipStream_t stream) {
  const float* x   = (const float*)d_in[0];
  const int*   ei  = (const int*)d_in[1];
  const float* ew  = (const float*)d_in[2];
  // d_in[3]=batch (implicit), d_in[5]=b1, d_in[9]=b2, d_in[13]=bf1 cancel
  // under training-mode BN and are unused.
  const float* W1  = (const float*)d_in[4];
  const float* g1  = (const float*)d_in[6];
  const float* be1 = (const float*)d_in[7];
  const float* W2  = (const float*)d_in[8];
  const float* g2  = (const float*)d_in[10];
  const float* be2 = (const float*)d_in[11];
  const float* Wf1 = (const float*)d_in[12];
  const float* gf  = (const float*)d_in[14];
  const float* bef = (const float*)d_in[15];
  const float* Wf2 = (const float*)d_in[16];
  const float* bf2 = (const float*)d_in[17];

  int N = in_sizes[3];   // 118784
  int E = in_sizes[2];   // 3801088
  int G = N / NPG;       // 1024

  float* ws    = (float*)d_ws;
  float* stats = ws;         // 256 floats (s1,q1,s2,q2)
  float* dinv  = ws + 256;   // N
  float* h1    = dinv + N;
  float* h2    = h1 + (size_t)N * HID;
  float* z     = h2 + (size_t)N * HID2;
  float* out   = (float*)d_out;
  float invN   = 1.0f / (float)N;

  hipMemsetAsync(stats, 0, 256 * sizeof(float), stream);
  k_conv1<<<G, 512, 0, stream>>>(x, ei, ew, W1, h1, dinv, stats, N, E);
  k_conv2<<<G, 512, 0, stream>>>(h1, ei, ew, W2, g1, be1, stats, dinv, h2,
                                 stats + 64, invN, N, E);
  k_pool<<<G, 256, 0, stream>>>(h2, g2, be2, stats + 64, Wf1, z, invN, N);
  k_final<<<1, 256, 0, stream>>>(z, gf, bef, Wf2, bf2, out, G);
}

// Round 7
// 732.375 us; speedup vs baseline: 2.6861x; 2.6861x over previous
//
#include <hip/hip_runtime.h>

#define NPG 116          // nodes per graph
#define DEGC 32          // edges per node
#define EPG (NPG * DEGC) // 3712 edges per graph
#define HID 32
#define HID2 64
#define EPS 1e-5f

#define AROWS 58         // A built in two 58-row halves (26.9 KB each)
#define L1S 33           // l1 row stride (floats)
#define YS4 9            // ysv row stride (float4)
#define NJC 29           // 116 floats = 29 float4

#define FMA4(acc, a, b)                                                        \
  acc.x += (a).x * (b).x; acc.y += (a).y * (b).y;                              \
  acc.z += (a).z * (b).z; acc.w += (a).w * (b).w;

#define HSUM4(v) (((v).x + (v).y) + ((v).z + (v).w))
#define F4Z make_float4(0.f, 0.f, 0.f, 0.f)

__device__ __forceinline__ float bf2f(unsigned short u) {
  union { unsigned int i; float f; } cv;
  cv.i = ((unsigned int)u) << 16;
  return cv.f;
}
__device__ __forceinline__ unsigned short f2bf(float f) {
  union { float f; unsigned int i; } cv;
  cv.f = f;
  unsigned int x = cv.i;
  x += 0x7fff + ((x >> 16) & 1);   // RNE
  return (unsigned short)(x >> 16);
}

// ---------------------------------------------------------------------------
// ws layout (floats):
//   [0,256)    stats: s1[32] q1[32] s2[64] q2[64]   (memset to 0 each launch)
//   [256, +N)     dinv (computed by conv1, reused by conv2)
//   [.., +32N)    h1  (conv1 output)
//   [.., +64N)    h2  (conv2 output)
//   [.., +32G)    z   (FC1 pre-BN)
// ---------------------------------------------------------------------------

// Fused per-graph conv1.  LDS ~42 KB (<=64 KB -> 2 blocks/CU).  gemm1 streams
// x from global (read-once); A built in two 58-row halves.
__global__ __launch_bounds__(512, 4) void k_conv1(const float* __restrict__ x,
                                                  const int* __restrict__ ei,
                                                  const float* __restrict__ ew,
                                                  const float* __restrict__ W1,
                                                  float* __restrict__ h1,
                                                  float* __restrict__ dinvg,
                                                  float* __restrict__ stats,
                                                  int N, int E) {
  __shared__ __align__(16) float Ah[AROWS * NPG];   // 26912 B
  __shared__ float l1[NPG * L1S];                   // 15312 B
  __shared__ float degs[NPG];
  __shared__ float ss[HID], qs[HID];
  int g = blockIdx.x, tid = threadIdx.x;
  int nb = g * NPG, e0 = g * EPG;
  const int* rowp = ei;
  const int* colp = ei + E;

  for (int i = tid; i < NPG; i += 512) degs[i] = 1.0f;  // self-loop weight
  if (tid < HID) { ss[tid] = 0.0f; qs[tid] = 0.0f; }
  {
    float4* Az = (float4*)Ah;
    for (int i = tid; i < AROWS * NJC; i += 512) Az[i] = F4Z;
  }
  __syncthreads();

  // phase 1: degree atomics + gemm1 (x streamed from global)
  for (int e = tid; e < EPG; e += 512) {
    int d = colp[e0 + e] - nb;
    atomicAdd(&degs[d], ew[e0 + e]);
  }
  const int c = tid & 31, rgrp = tid >> 5;  // 16 row groups
  float4 col[NJC];
#pragma unroll
  for (int kc = 0; kc < NJC; ++kc) {
    col[kc].x = W1[(4 * kc + 0) * 32 + c];
    col[kc].y = W1[(4 * kc + 1) * 32 + c];
    col[kc].z = W1[(4 * kc + 2) * 32 + c];
    col[kc].w = W1[(4 * kc + 3) * 32 + c];
  }
  {
    int r = rgrp;
    for (; r + 16 < NPG; r += 32) {
      const float4* pa = (const float4*)(x + (size_t)(nb + r) * NPG);
      const float4* pb = (const float4*)(x + (size_t)(nb + r + 16) * NPG);
      float4 a0 = F4Z, a1 = F4Z;
#pragma unroll
      for (int jc = 0; jc < NJC; ++jc) {
        FMA4(a0, pa[jc], col[jc]);
        FMA4(a1, pb[jc], col[jc]);
      }
      l1[r * L1S + c] = HSUM4(a0);
      l1[(r + 16) * L1S + c] = HSUM4(a1);
    }
    if (r < NPG) {
      const float4* pa = (const float4*)(x + (size_t)(nb + r) * NPG);
      float4 a0 = F4Z;
#pragma unroll
      for (int jc = 0; jc < NJC; ++jc) { FMA4(a0, pa[jc], col[jc]); }
      l1[r * L1S + c] = HSUM4(a0);
    }
  }
  __syncthreads();  // degs + l1 complete

  for (int i = tid; i < NPG; i += 512) {
    float dv = rsqrtf(degs[i]);   // deg >= 1
    degs[i] = dv;
    dinvg[nb + i] = dv;
  }
  __syncthreads();  // dinv ready, Ah zeroed

  // build Ah half0 (d<58); reload col regs with l1 column c meanwhile
  for (int e = tid; e < EPG; e += 512) {
    int eg = e0 + e;
    int s = rowp[eg] - nb, d = colp[eg] - nb;
    if (d < AROWS) atomicAdd(&Ah[d * NPG + s], degs[s] * ew[eg] * degs[d]);
  }
  for (int i = tid; i < AROWS; i += 512)
    atomicAdd(&Ah[i * NPG + i], degs[i] * degs[i]);
#pragma unroll
  for (int kc = 0; kc < NJC; ++kc) {
    col[kc].x = l1[(4 * kc + 0) * L1S + c];
    col[kc].y = l1[(4 * kc + 1) * L1S + c];
    col[kc].z = l1[(4 * kc + 2) * L1S + c];
    col[kc].w = l1[(4 * kc + 3) * L1S + c];
  }
  __syncthreads();  // Ah half0 built

  const float4* A4 = (const float4*)Ah;
  float s_ = 0.0f, q_ = 0.0f;

#define PASS1(ROW_OFF)                                                         \
  {                                                                            \
    int r = rgrp;                                                              \
    for (; r + 16 < AROWS; r += 32) {                                          \
      const float4* pa = A4 + r * NJC;                                         \
      const float4* pb = A4 + (r + 16) * NJC;                                  \
      float4 a0 = F4Z, a1 = F4Z;                                               \
      _Pragma("unroll")                                                        \
      for (int jc = 0; jc < NJC; ++jc) {                                       \
        FMA4(a0, pa[jc], col[jc]);                                             \
        FMA4(a1, pb[jc], col[jc]);                                             \
      }                                                                        \
      float v0 = HSUM4(a0), v1 = HSUM4(a1);                                    \
      h1[(size_t)(nb + (ROW_OFF) + r) * HID + c] = v0;                         \
      h1[(size_t)(nb + (ROW_OFF) + r + 16) * HID + c] = v1;                    \
      s_ += v0 + v1; q_ += v0 * v0 + v1 * v1;                                  \
    }                                                                          \
    if (r < AROWS) {                                                           \
      const float4* pa = A4 + r * NJC;                                         \
      float4 a0 = F4Z;                                                         \
      _Pragma("unroll")                                                        \
      for (int jc = 0; jc < NJC; ++jc) { FMA4(a0, pa[jc], col[jc]); }          \
      float v0 = HSUM4(a0);                                                    \
      h1[(size_t)(nb + (ROW_OFF) + r) * HID + c] = v0;                         \
      s_ += v0; q_ += v0 * v0;                                                 \
    }                                                                          \
  }

  PASS1(0)
  __syncthreads();  // half0 reads done
  {
    float4* Az = (float4*)Ah;
    for (int i = tid; i < AROWS * NJC; i += 512) Az[i] = F4Z;
  }
  __syncthreads();
  for (int e = tid; e < EPG; e += 512) {
    int eg = e0 + e;
    int s = rowp[eg] - nb, d = colp[eg] - nb;
    if (d >= AROWS)
      atomicAdd(&Ah[(d - AROWS) * NPG + s], degs[s] * ew[eg] * degs[d]);
  }
  for (int i = tid; i < AROWS; i += 512) {
    int ii = i + AROWS;
    atomicAdd(&Ah[i * NPG + ii], degs[ii] * degs[ii]);
  }
  __syncthreads();  // Ah half1 built
  PASS1(AROWS)
#undef PASS1

  atomicAdd(&ss[c], s_);
  atomicAdd(&qs[c], q_);
  __syncthreads();
  if (tid < HID) {
    atomicAdd(&stats[tid], ss[tid]);
    atomicAdd(&stats[32 + tid], qs[tid]);
  }
}

// Fused per-graph conv2.  LDS ~58 KB (<=64 KB -> 2 blocks/CU).  l2 stored
// bf16; A in two 58-row halves; dinv from ws; BN1 coefs computed per block.
__global__ __launch_bounds__(512, 4) void k_conv2(const float* __restrict__ h1,
                                                  const int* __restrict__ ei,
                                                  const float* __restrict__ ew,
                                                  const float* __restrict__ W2,
                                                  const float* __restrict__ g1,
                                                  const float* __restrict__ be1,
                                                  const float* __restrict__ stats,
                                                  const float* __restrict__ dinvg,
                                                  float* __restrict__ h2,
                                                  float* __restrict__ stats2,
                                                  float invN,
                                                  int N, int E) {
  __shared__ __align__(16) float Ah[AROWS * NPG];     // 26912 B
  __shared__ __align__(16) float4 ysv[NPG * YS4];     // 16704 B
  __shared__ unsigned short l2b[NPG * HID2];          // 14848 B
  __shared__ float degs[NPG];
  __shared__ float ss[HID2], qs[HID2];
  __shared__ float a1s[HID], c1s[HID];
  int g = blockIdx.x, tid = threadIdx.x;
  int nb = g * NPG, e0 = g * EPG;
  const int* rowp = ei;
  const int* colp = ei + E;

  if (tid < HID) {
    float m = stats[tid] * invN;
    float v = stats[32 + tid] * invN - m * m;
    float a = g1[tid] * rsqrtf(v + EPS);
    a1s[tid] = a;
    c1s[tid] = be1[tid] - m * a;
  }
  if (tid < HID2) { ss[tid] = 0.0f; qs[tid] = 0.0f; }
  __syncthreads();

  // phase 1: stage ys = relu(a1*h1+c1), load dinv, zero Ah
  {
    const float4* hg = (const float4*)(h1 + (size_t)nb * HID);
    for (int i = tid; i < NPG * 8; i += 512) {
      int r = i >> 3, kc = i & 7, k0 = kc * 4;
      float4 hv = hg[i];
      float4 y;
      y.x = fmaxf(0.f, a1s[k0 + 0] * hv.x + c1s[k0 + 0]);
      y.y = fmaxf(0.f, a1s[k0 + 1] * hv.y + c1s[k0 + 1]);
      y.z = fmaxf(0.f, a1s[k0 + 2] * hv.z + c1s[k0 + 2]);
      y.w = fmaxf(0.f, a1s[k0 + 3] * hv.w + c1s[k0 + 3]);
      ysv[r * YS4 + kc] = y;
    }
    for (int i = tid; i < NPG; i += 512) degs[i] = dinvg[nb + i];
    float4* Az = (float4*)Ah;
    for (int i = tid; i < AROWS * NJC; i += 512) Az[i] = F4Z;
  }
  __syncthreads();

  const int c = tid & 63, rgrp = tid >> 6;   // 8 row groups

  // phase 2: build Ah half0 atomics (latency) overlap gemm2 (compute)
  for (int e = tid; e < EPG; e += 512) {
    int eg = e0 + e;
    int s = rowp[eg] - nb, d = colp[eg] - nb;
    if (d < AROWS) atomicAdd(&Ah[d * NPG + s], degs[s] * ew[eg] * degs[d]);
  }
  for (int i = tid; i < AROWS; i += 512)
    atomicAdd(&Ah[i * NPG + i], degs[i] * degs[i]);

  {
    float4 w2c[8];
#pragma unroll
    for (int kc = 0; kc < 8; ++kc) {
      w2c[kc].x = W2[(4 * kc + 0) * 64 + c];
      w2c[kc].y = W2[(4 * kc + 1) * 64 + c];
      w2c[kc].z = W2[(4 * kc + 2) * 64 + c];
      w2c[kc].w = W2[(4 * kc + 3) * 64 + c];
    }
    int r = rgrp;
    for (; r + 8 < NPG; r += 16) {
      float4 a0 = F4Z, a1 = F4Z;
#pragma unroll
      for (int kc = 0; kc < 8; ++kc) {
        FMA4(a0, ysv[r * YS4 + kc], w2c[kc]);
        FMA4(a1, ysv[(r + 8) * YS4 + kc], w2c[kc]);
      }
      l2b[r * HID2 + c] = f2bf(HSUM4(a0));
      l2b[(r + 8) * HID2 + c] = f2bf(HSUM4(a1));
    }
    if (r < NPG) {
      float4 a0 = F4Z;
#pragma unroll
      for (int kc = 0; kc < 8; ++kc) { FMA4(a0, ysv[r * YS4 + kc], w2c[kc]); }
      l2b[r * HID2 + c] = f2bf(HSUM4(a0));
    }
  }
  __syncthreads();  // Ah half0 + l2b complete

  float4 col[NJC];
#pragma unroll
  for (int kc = 0; kc < NJC; ++kc) {
    col[kc].x = bf2f(l2b[(4 * kc + 0) * HID2 + c]);
    col[kc].y = bf2f(l2b[(4 * kc + 1) * HID2 + c]);
    col[kc].z = bf2f(l2b[(4 * kc + 2) * HID2 + c]);
    col[kc].w = bf2f(l2b[(4 * kc + 3) * HID2 + c]);
  }
  const float4* A4 = (const float4*)Ah;
  float s_ = 0.0f, q_ = 0.0f;

#define PASS2(ROW_OFF)                                                         \
  {                                                                            \
    int r = rgrp;                                                              \
    for (; r + 8 < AROWS; r += 16) {                                           \
      const float4* pa = A4 + r * NJC;                                         \
      const float4* pb = A4 + (r + 8) * NJC;                                   \
      float4 a0 = F4Z, a1 = F4Z;                                               \
      _Pragma("unroll")                                                        \
      for (int jc = 0; jc < NJC; ++jc) {                                       \
        FMA4(a0, pa[jc], col[jc]);                                             \
        FMA4(a1, pb[jc], col[jc]);                                             \
      }                                                                        \
      float v0 = HSUM4(a0), v1 = HSUM4(a1);                                    \
      h2[(size_t)(nb + (ROW_OFF) + r) * HID2 + c] = v0;                        \
      h2[(size_t)(nb + (ROW_OFF) + r + 8) * HID2 + c] = v1;                    \
      s_ += v0 + v1; q_ += v0 * v0 + v1 * v1;                                  \
    }                                                                          \
    if (r < AROWS) {                                                           \
      const float4* pa = A4 + r * NJC;                                         \
      float4 a0 = F4Z;                                                         \
      _Pragma("unroll")                                                        \
      for (int jc = 0; jc < NJC; ++jc) { FMA4(a0, pa[jc], col[jc]); }          \
      float v0 = HSUM4(a0);                                                    \
      h2[(size_t)(nb + (ROW_OFF) + r) * HID2 + c] = v0;                        \
      s_ += v0; q_ += v0 * v0;                                                 \
    }                                                                          \
  }

  PASS2(0)
  __syncthreads();  // half0 reads done
  {
    float4* Az = (float4*)Ah;
    for (int i = tid; i < AROWS * NJC; i += 512) Az[i] = F4Z;
  }
  __syncthreads();
  for (int e = tid; e < EPG; e += 512) {
    int eg = e0 + e;
    int s = rowp[eg] - nb, d = colp[eg] - nb;
    if (d >= AROWS)
      atomicAdd(&Ah[(d - AROWS) * NPG + s], degs[s] * ew[eg] * degs[d]);
  }
  for (int i = tid; i < AROWS; i += 512) {
    int ii = i + AROWS;
    atomicAdd(&Ah[i * NPG + ii], degs[ii] * degs[ii]);
  }
  __syncthreads();  // Ah half1 built
  PASS2(AROWS)
#undef PASS2

  atomicAdd(&ss[c], s_);
  atomicAdd(&qs[c], q_);
  __syncthreads();
  if (tid < HID2) {
    atomicAdd(&stats2[tid], ss[tid]);
    atomicAdd(&stats2[64 + tid], qs[tid]);
  }
}

// per-graph BN2 coefs (per-block) + relu, mean/max pool, FC1 -> z
__global__ __launch_bounds__(256) void k_pool(const float* __restrict__ h2,
                                              const float* __restrict__ g2,
                                              const float* __restrict__ be2,
                                              const float* __restrict__ stats2,
                                              const float* __restrict__ Wf1,
                                              float* __restrict__ z,
                                              float invN, int N) {
  __shared__ float4 psum4[256], pmax4[256];
  __shared__ __align__(16) float emb[128];
  __shared__ __align__(16) float a2s[HID2], c2s[HID2];
  int g = blockIdx.x, tid = threadIdx.x;
  if (tid < HID2) {
    float m = stats2[tid] * invN;
    float v = stats2[64 + tid] * invN - m * m;
    float a = g2[tid] * rsqrtf(v + EPS);
    a2s[tid] = a;
    c2s[tid] = be2[tid] - m * a;
  }
  __syncthreads();
  int c4 = tid & 15, rg = tid >> 4;
  float4 av = ((const float4*)a2s)[c4], bv = ((const float4*)c2s)[c4];
  const float4* h4 = (const float4*)h2 + (size_t)g * NPG * 16;
  float4 s = {0.f, 0.f, 0.f, 0.f};
  float4 mx = {-1e30f, -1e30f, -1e30f, -1e30f};
  for (int n = rg; n < NPG; n += 16) {
    float4 v = h4[n * 16 + c4];
    float4 y;
    y.x = fmaxf(0.f, av.x * v.x + bv.x);
    y.y = fmaxf(0.f, av.y * v.y + bv.y);
    y.z = fmaxf(0.f, av.z * v.z + bv.z);
    y.w = fmaxf(0.f, av.w * v.w + bv.w);
    s.x += y.x; s.y += y.y; s.z += y.z; s.w += y.w;
    mx.x = fmaxf(mx.x, y.x); mx.y = fmaxf(mx.y, y.y);
    mx.z = fmaxf(mx.z, y.z); mx.w = fmaxf(mx.w, y.w);
  }
  psum4[rg * 16 + c4] = s;
  pmax4[rg * 16 + c4] = mx;
  __syncthreads();
  if (tid < 16) {
    float4 S = psum4[tid], M = pmax4[tid];
    for (int j = 1; j < 16; ++j) {
      float4 p = psum4[j * 16 + tid], q = pmax4[j * 16 + tid];
      S.x += p.x; S.y += p.y; S.z += p.z; S.w += p.w;
      M.x = fmaxf(M.x, q.x); M.y = fmaxf(M.y, q.y);
      M.z = fmaxf(M.z, q.z); M.w = fmaxf(M.w, q.w);
    }
    const float inv = 1.0f / NPG;
    ((float4*)emb)[tid] = make_float4(S.x * inv, S.y * inv, S.z * inv, S.w * inv);
    ((float4*)emb)[16 + tid] = M;
  }
  __syncthreads();
  if (tid < 32) {
    float acc = 0.0f;
#pragma unroll
    for (int k = 0; k < 128; ++k) acc += emb[k] * Wf1[k * 32 + tid];
    z[g * 32 + tid] = acc;
  }
}

// single block: BNf stats over z (G x 32) -> coeffs -> relu -> FC2 -> out
__global__ __launch_bounds__(256) void k_final(const float* __restrict__ z,
                                               const float* __restrict__ gf,
                                               const float* __restrict__ bef,
                                               const float* __restrict__ Wf2,
                                               const float* __restrict__ bf2,
                                               float* __restrict__ out, int G) {
  __shared__ float ss[32], qs[32], af[32], cf[32];
  __shared__ float w2s[64], b2s[2];
  int tid = threadIdx.x;
  if (tid < 32) { ss[tid] = 0.0f; qs[tid] = 0.0f; }
  if (tid < 64) w2s[tid] = Wf2[tid];
  if (tid < 2) b2s[tid] = bf2[tid];
  __syncthreads();
  const float4* z4 = (const float4*)z;
  int n4 = G * 8;
  float4 s = {0.f, 0.f, 0.f, 0.f}, q = {0.f, 0.f, 0.f, 0.f};
  for (int i = tid; i < n4; i += 256) {
    float4 v = z4[i];
    s.x += v.x; s.y += v.y; s.z += v.z; s.w += v.w;
    q.x += v.x * v.x; q.y += v.y * v.y; q.z += v.z * v.z; q.w += v.w * v.w;
  }
  int cg = (tid & 7) * 4;
  atomicAdd(&ss[cg + 0], s.x); atomicAdd(&ss[cg + 1], s.y);
  atomicAdd(&ss[cg + 2], s.z); atomicAdd(&ss[cg + 3], s.w);
  atomicAdd(&qs[cg + 0], q.x); atomicAdd(&qs[cg + 1], q.y);
  atomicAdd(&qs[cg + 2], q.z); atomicAdd(&qs[cg + 3], q.w);
  __syncthreads();
  if (tid < 32) {
    float invG = 1.0f / G;
    float m = ss[tid] * invG;
    float v = qs[tid] * invG - m * m;
    float a = gf[tid] * rsqrtf(v + EPS);
    af[tid] = a;
    cf[tid] = bef[tid] - m * a;
  }
  __syncthreads();
  for (int g = tid; g < G; g += 256) {
    float o0 = b2s[0], o1 = b2s[1];
    const float4* zr = z4 + g * 8;
#pragma unroll
    for (int kc = 0; kc < 8; ++kc) {
      float4 v = zr[kc];
      int j = 4 * kc;
      float y;
      y = fmaxf(0.f, af[j + 0] * v.x + cf[j + 0]);
      o0 += y * w2s[2 * (j + 0)]; o1 += y * w2s[2 * (j + 0) + 1];
      y = fmaxf(0.f, af[j + 1] * v.y + cf[j + 1]);
      o0 += y * w2s[2 * (j + 1)]; o1 += y * w2s[2 * (j + 1) + 1];
      y = fmaxf(0.f, af[j + 2] * v.z + cf[j + 2]);
      o0 += y * w2s[2 * (j + 2)]; o1 += y * w2s[2 * (j + 2) + 1];
      y = fmaxf(0.f, af[j + 3] * v.w + cf[j + 3]);
      o0 += y * w2s[2 * (j + 3)]; o1 += y * w2s[2 * (j + 3) + 1];
    }
    out[g * 2] = o0;
    out[g * 2 + 1] = o1;
  }
}

extern "C" void kernel_launch(void* const* d_in, const int* in_sizes, int n_in,
                              void* d_out, int out_size, void* d_ws, size_t ws_size,
                              hipStream_t stream) {
  const float* x   = (const float*)d_in[0];
  const int*   ei  = (const int*)d_in[1];
  const float* ew  = (const float*)d_in[2];
  // d_in[3]=batch (implicit), d_in[5]=b1, d_in[9]=b2, d_in[13]=bf1 cancel
  // under training-mode BN and are unused.
  const float* W1  = (const float*)d_in[4];
  const float* g1  = (const float*)d_in[6];
  const float* be1 = (const float*)d_in[7];
  const float* W2  = (const float*)d_in[8];
  const float* g2  = (const float*)d_in[10];
  const float* be2 = (const float*)d_in[11];
  const float* Wf1 = (const float*)d_in[12];
  const float* gf  = (const float*)d_in[14];
  const float* bef = (const float*)d_in[15];
  const float* Wf2 = (const float*)d_in[16];
  const float* bf2 = (const float*)d_in[17];

  int N = in_sizes[3];   // 118784
  int E = in_sizes[2];   // 3801088
  int G = N / NPG;       // 1024

  float* ws    = (float*)d_ws;
  float* stats = ws;         // 256 floats (s1,q1,s2,q2)
  float* dinv  = ws + 256;   // N
  float* h1    = dinv + N;
  float* h2    = h1 + (size_t)N * HID;
  float* z     = h2 + (size_t)N * HID2;
  float* out   = (float*)d_out;
  float invN   = 1.0f / (float)N;

  hipMemsetAsync(stats, 0, 256 * sizeof(float), stream);
  k_conv1<<<G, 512, 0, stream>>>(x, ei, ew, W1, h1, dinv, stats, N, E);
  k_conv2<<<G, 512, 0, stream>>>(h1, ei, ew, W2, g1, be1, stats, dinv, h2,
                                 stats + 64, invN, N, E);
  k_pool<<<G, 256, 0, stream>>>(h2, g2, be2, stats + 64, Wf1, z, invN, N);
  k_final<<<1, 256, 0, stream>>>(z, gf, bef, Wf2, bf2, out, G);
}

// Round 8
// 210.886 us; speedup vs baseline: 9.3283x; 3.4728x over previous
//
#include <hip/hip_runtime.h>

#define NPG 116          // nodes per graph
#define EPG (NPG * 32)   // 3712 edges per graph
#define HID 32
#define HID2 64
#define EPS 1e-5f

#define AS 136           // bf16 tile k-stride (shorts): 272B = 16B-aligned, uniform banks
#define YSS 40           // ysb/W2T k-stride (shorts)

using bf16x8 = __attribute__((ext_vector_type(8))) short;
using f32x4  = __attribute__((ext_vector_type(4))) float;

__device__ __forceinline__ unsigned short f2bf(float f) {
  union { float f; unsigned int i; } cv;
  cv.f = f;
  unsigned int x = cv.i;
  x += 0x7fff + ((x >> 16) & 1);   // RNE
  return (unsigned short)(x >> 16);
}

#define MFMA16(a, b, c) __builtin_amdgcn_mfma_f32_16x16x32_bf16((a), (b), (c), 0, 0, 0)

// ---------------------------------------------------------------------------
// ws layout (floats):
//   [0,256)   stats: s1[32] q1[32] s2[64] q2[64]  (memset 0 each launch)
//   [256,+N)  dinv; then h1 (32N), h2 (64N), z (32G)
// ---------------------------------------------------------------------------

// conv1: deg -> gemm1 = X@W1 (MFMA, X frags from global) -> A-build (fp32 LDS
// atomics) -> A->bf16 -> h1 = A@L1 (MFMA) + BN1 stat partials.  512 thr.
__global__ __launch_bounds__(512) void k_conv1(const float* __restrict__ x,
                                               const int* __restrict__ ei,
                                               const float* __restrict__ ew,
                                               const float* __restrict__ W1,
                                               float* __restrict__ h1,
                                               float* __restrict__ dinvg,
                                               float* __restrict__ stats,
                                               int N, int E) {
  __shared__ __align__(16) float Af[NPG * NPG];        // 53.8 KB fp32 adjacency
  __shared__ __align__(16) short Ab[128 * AS];         // 34.8 KB bf16 adjacency
  __shared__ __align__(16) short W1T[HID * AS];        // 8.7 KB  W1 transposed
  __shared__ __align__(16) short L1T[HID * AS];        // 8.7 KB  lin1 transposed
  __shared__ float degs[NPG];
  __shared__ float ss[HID], qs[HID];
  const int g = blockIdx.x, tid = threadIdx.x;
  const int nb = g * NPG, e0 = g * EPG;
  const int* rowp = ei;
  const int* colp = ei + E;
  const int l = tid & 63, w = tid >> 6;
  const int rf = l & 15, kg = l >> 4;

  // P0a: zero everything (pads must be 0 for MFMA k/m padding)
  for (int i = tid; i < NPG; i += 512) degs[i] = 1.0f;  // self-loop weight
  if (tid < HID) { ss[tid] = 0.0f; qs[tid] = 0.0f; }
  { float4* p = (float4*)Af;
    for (int i = tid; i < NPG * 29; i += 512) p[i] = make_float4(0,0,0,0); }
  { int* p = (int*)Ab;
    for (int i = tid; i < 128 * AS / 2; i += 512) p[i] = 0; }
  { int* p = (int*)W1T;
    for (int i = tid; i < HID * AS / 2; i += 512) p[i] = 0; }
  { int* p = (int*)L1T;
    for (int i = tid; i < HID * AS / 2; i += 512) p[i] = 0; }
  __syncthreads();

  // P0b: stage W1T bf16, degree atomics
  for (int i = tid; i < NPG * HID; i += 512) {
    int k = i >> 5, c = i & 31;
    W1T[c * AS + k] = (short)f2bf(W1[i]);
  }
  for (int e = tid; e < EPG; e += 512) {
    int d = colp[e0 + e] - nb;
    atomicAdd(&degs[d], ew[e0 + e]);
  }
  __syncthreads();

  // P1: dinv
  for (int i = tid; i < NPG; i += 512) {
    float dv = rsqrtf(degs[i]);   // deg >= 1
    degs[i] = dv;
    dinvg[nb + i] = dv;
  }
  __syncthreads();

  // P2: A-build atomics (latency) + gemm1 MFMA (compute) -> L1T
  for (int e = tid; e < EPG; e += 512) {
    int eg = e0 + e;
    int s = rowp[eg] - nb, d = colp[eg] - nb;
    atomicAdd(&Af[d * NPG + s], degs[s] * ew[eg] * degs[d]);
  }
  for (int i = tid; i < NPG; i += 512)
    atomicAdd(&Af[i * NPG + i], degs[i] * degs[i]);

  for (int t = w; t < 16; t += 8) {       // 2 tiles per wave: (mt, nt)
    const int mt = t >> 1, nt = t & 1;
    const int rl = mt * 16 + rf;
    f32x4 acc = {0.f, 0.f, 0.f, 0.f};
#pragma unroll
    for (int kk = 0; kk < 4; ++kk) {
      bf16x8 a;
      if (rl < NPG) {
        const float* xr = x + (size_t)(nb + rl) * NPG;
        if (kk < 3) {
          const float4* xp = (const float4*)(xr + kk * 32 + kg * 8);
          float4 v0 = xp[0], v1 = xp[1];
          a[0] = (short)f2bf(v0.x); a[1] = (short)f2bf(v0.y);
          a[2] = (short)f2bf(v0.z); a[3] = (short)f2bf(v0.w);
          a[4] = (short)f2bf(v1.x); a[5] = (short)f2bf(v1.y);
          a[6] = (short)f2bf(v1.z); a[7] = (short)f2bf(v1.w);
        } else {
          const int k0 = 96 + kg * 8;
#pragma unroll
          for (int j = 0; j < 8; ++j) {
            int k = k0 + j;
            a[j] = (k < NPG) ? (short)f2bf(xr[k]) : (short)0;
          }
        }
      } else {
#pragma unroll
        for (int j = 0; j < 8; ++j) a[j] = 0;
      }
      bf16x8 b = *(const bf16x8*)&W1T[(nt * 16 + rf) * AS + kk * 32 + kg * 8];
      acc = MFMA16(a, b, acc);
    }
    const int col = nt * 16 + rf;
#pragma unroll
    for (int i = 0; i < 4; ++i) {
      int row = mt * 16 + kg * 4 + i;
      if (row < NPG) L1T[col * AS + row] = (short)f2bf(acc[i]);
    }
  }
  __syncthreads();   // Af built, L1T complete

  // P3: Af -> Ab (bf16)
  for (int r = w; r < NPG; r += 8)
    for (int j = l; j < NPG; j += 64)
      Ab[r * AS + j] = (short)f2bf(Af[r * NPG + j]);
  __syncthreads();

  // P4: h1 = A @ L1 (MFMA) + stats
  for (int t = w; t < 16; t += 8) {
    const int mt = t >> 1, nt = t & 1;
    f32x4 acc = {0.f, 0.f, 0.f, 0.f};
#pragma unroll
    for (int kk = 0; kk < 4; ++kk) {
      bf16x8 a = *(const bf16x8*)&Ab[(mt * 16 + rf) * AS + kk * 32 + kg * 8];
      bf16x8 b = *(const bf16x8*)&L1T[(nt * 16 + rf) * AS + kk * 32 + kg * 8];
      acc = MFMA16(a, b, acc);
    }
    const int col = nt * 16 + rf;
    float s_ = 0.f, q_ = 0.f;
#pragma unroll
    for (int i = 0; i < 4; ++i) {
      int row = mt * 16 + kg * 4 + i;
      if (row < NPG) {
        float v = acc[i];
        h1[(size_t)(nb + row) * HID + col] = v;
        s_ += v; q_ += v * v;
      }
    }
    atomicAdd(&ss[col], s_);
    atomicAdd(&qs[col], q_);
  }
  __syncthreads();
  if (tid < HID) {
    atomicAdd(&stats[tid], ss[tid]);
    atomicAdd(&stats[32 + tid], qs[tid]);
  }
}

// conv2: BN1 coefs -> ys=relu(a1*h1+c1) bf16 -> gemm2 = ys@W2 (MFMA) ->
// A rebuild -> bf16 -> h2 = A@L2 (MFMA) + BN2 stat partials.
__global__ __launch_bounds__(512) void k_conv2(const float* __restrict__ h1,
                                               const int* __restrict__ ei,
                                               const float* __restrict__ ew,
                                               const float* __restrict__ W2,
                                               const float* __restrict__ g1,
                                               const float* __restrict__ be1,
                                               const float* __restrict__ stats,
                                               const float* __restrict__ dinvg,
                                               float* __restrict__ h2,
                                               float* __restrict__ stats2,
                                               float invN,
                                               int N, int E) {
  __shared__ __align__(16) float Af[NPG * NPG];        // 53.8 KB
  __shared__ __align__(16) short Ab[128 * AS];         // 34.8 KB
  __shared__ __align__(16) short ysb[128 * YSS];       // 10.2 KB
  __shared__ __align__(16) short W2T[HID2 * YSS];      // 5.1 KB
  __shared__ __align__(16) short L2T[HID2 * AS];       // 17.4 KB
  __shared__ float degs[NPG];
  __shared__ float ss[HID2], qs[HID2];
  __shared__ float a1s[HID], c1s[HID];
  const int g = blockIdx.x, tid = threadIdx.x;
  const int nb = g * NPG, e0 = g * EPG;
  const int* rowp = ei;
  const int* colp = ei + E;
  const int l = tid & 63, w = tid >> 6;
  const int rf = l & 15, kg = l >> 4;

  // P0a: coefs, zeros, dinv load
  if (tid < HID) {
    float m = stats[tid] * invN;
    float v = stats[32 + tid] * invN - m * m;
    float a = g1[tid] * rsqrtf(v + EPS);
    a1s[tid] = a;
    c1s[tid] = be1[tid] - m * a;
  }
  if (tid < HID2) { ss[tid] = 0.0f; qs[tid] = 0.0f; }
  { float4* p = (float4*)Af;
    for (int i = tid; i < NPG * 29; i += 512) p[i] = make_float4(0,0,0,0); }
  { int* p = (int*)Ab;
    for (int i = tid; i < 128 * AS / 2; i += 512) p[i] = 0; }
  { int* p = (int*)L2T;
    for (int i = tid; i < HID2 * AS / 2; i += 512) p[i] = 0; }
  { int* p = (int*)ysb;
    for (int i = tid; i < 128 * YSS / 2; i += 512) p[i] = 0; }
  for (int i = tid; i < NPG; i += 512) degs[i] = dinvg[nb + i];
  __syncthreads();

  // P0b: stage ysb = bf16(relu(a1*h1+c1)), W2T; A-build atomics
  {
    const float4* hg = (const float4*)(h1 + (size_t)nb * HID);
    for (int i = tid; i < NPG * 8; i += 512) {
      int r = i >> 3, kc = i & 7, k0 = kc * 4;
      float4 hv = hg[i];
      float y0 = fmaxf(0.f, a1s[k0 + 0] * hv.x + c1s[k0 + 0]);
      float y1 = fmaxf(0.f, a1s[k0 + 1] * hv.y + c1s[k0 + 1]);
      float y2 = fmaxf(0.f, a1s[k0 + 2] * hv.z + c1s[k0 + 2]);
      float y3 = fmaxf(0.f, a1s[k0 + 3] * hv.w + c1s[k0 + 3]);
      unsigned int u0 = (unsigned)f2bf(y0) | ((unsigned)f2bf(y1) << 16);
      unsigned int u1 = (unsigned)f2bf(y2) | ((unsigned)f2bf(y3) << 16);
      *(unsigned int*)&ysb[r * YSS + k0] = u0;
      *(unsigned int*)&ysb[r * YSS + k0 + 2] = u1;
    }
    for (int i = tid; i < HID * HID2; i += 512) {
      int k = i >> 6, c = i & 63;
      W2T[c * YSS + k] = (short)f2bf(W2[i]);
    }
    for (int e = tid; e < EPG; e += 512) {
      int eg = e0 + e;
      int s = rowp[eg] - nb, d = colp[eg] - nb;
      atomicAdd(&Af[d * NPG + s], degs[s] * ew[eg] * degs[d]);
    }
    for (int i = tid; i < NPG; i += 512)
      atomicAdd(&Af[i * NPG + i], degs[i] * degs[i]);
  }
  __syncthreads();

  // P1: gemm2 MFMA (K=32, 1 k-step); wave w owns m-tile w, all 4 n-tiles
  {
    const int mt = w;
    bf16x8 a = *(const bf16x8*)&ysb[(mt * 16 + rf) * YSS + kg * 8];
#pragma unroll
    for (int nt = 0; nt < 4; ++nt) {
      f32x4 acc = {0.f, 0.f, 0.f, 0.f};
      bf16x8 b = *(const bf16x8*)&W2T[(nt * 16 + rf) * YSS + kg * 8];
      acc = MFMA16(a, b, acc);
      const int col = nt * 16 + rf;
#pragma unroll
      for (int i = 0; i < 4; ++i) {
        int row = mt * 16 + kg * 4 + i;
        if (row < NPG) L2T[col * AS + row] = (short)f2bf(acc[i]);
      }
    }
  }
  __syncthreads();   // Af + L2T complete

  // P2: Af -> Ab
  for (int r = w; r < NPG; r += 8)
    for (int j = l; j < NPG; j += 64)
      Ab[r * AS + j] = (short)f2bf(Af[r * NPG + j]);
  __syncthreads();

  // P3: h2 = A @ L2 (MFMA): wave w -> m-tile w, 4 n-tiles, 4 k-steps
  {
    const int mt = w;
    f32x4 acc[4];
#pragma unroll
    for (int nt = 0; nt < 4; ++nt) acc[nt] = (f32x4){0.f, 0.f, 0.f, 0.f};
#pragma unroll
    for (int kk = 0; kk < 4; ++kk) {
      bf16x8 a = *(const bf16x8*)&Ab[(mt * 16 + rf) * AS + kk * 32 + kg * 8];
#pragma unroll
      for (int nt = 0; nt < 4; ++nt) {
        bf16x8 b = *(const bf16x8*)&L2T[(nt * 16 + rf) * AS + kk * 32 + kg * 8];
        acc[nt] = MFMA16(a, b, acc[nt]);
      }
    }
#pragma unroll
    for (int nt = 0; nt < 4; ++nt) {
      const int col = nt * 16 + rf;
      float s_ = 0.f, q_ = 0.f;
#pragma unroll
      for (int i = 0; i < 4; ++i) {
        int row = mt * 16 + kg * 4 + i;
        if (row < NPG) {
          float v = acc[nt][i];
          h2[(size_t)(nb + row) * HID2 + col] = v;
          s_ += v; q_ += v * v;
        }
      }
      atomicAdd(&ss[col], s_);
      atomicAdd(&qs[col], q_);
    }
  }
  __syncthreads();
  if (tid < HID2) {
    atomicAdd(&stats2[tid], ss[tid]);
    atomicAdd(&stats2[64 + tid], qs[tid]);
  }
}

// per-graph BN2 coefs + relu, mean/max pool, FC1 -> z
__global__ __launch_bounds__(256) void k_pool(const float* __restrict__ h2,
                                              const float* __restrict__ g2,
                                              const float* __restrict__ be2,
                                              const float* __restrict__ stats2,
                                              const float* __restrict__ Wf1,
                                              float* __restrict__ z,
                                              float invN, int N) {
  __shared__ float4 psum4[256], pmax4[256];
  __shared__ __align__(16) float emb[128];
  __shared__ __align__(16) float a2s[HID2], c2s[HID2];
  int g = blockIdx.x, tid = threadIdx.x;
  if (tid < HID2) {
    float m = stats2[tid] * invN;
    float v = stats2[64 + tid] * invN - m * m;
    float a = g2[tid] * rsqrtf(v + EPS);
    a2s[tid] = a;
    c2s[tid] = be2[tid] - m * a;
  }
  __syncthreads();
  int c4 = tid & 15, rg = tid >> 4;
  float4 av = ((const float4*)a2s)[c4], bv = ((const float4*)c2s)[c4];
  const float4* h4 = (const float4*)h2 + (size_t)g * NPG * 16;
  float4 s = {0.f, 0.f, 0.f, 0.f};
  float4 mx = {-1e30f, -1e30f, -1e30f, -1e30f};
  for (int n = rg; n < NPG; n += 16) {
    float4 v = h4[n * 16 + c4];
    float4 y;
    y.x = fmaxf(0.f, av.x * v.x + bv.x);
    y.y = fmaxf(0.f, av.y * v.y + bv.y);
    y.z = fmaxf(0.f, av.z * v.z + bv.z);
    y.w = fmaxf(0.f, av.w * v.w + bv.w);
    s.x += y.x; s.y += y.y; s.z += y.z; s.w += y.w;
    mx.x = fmaxf(mx.x, y.x); mx.y = fmaxf(mx.y, y.y);
    mx.z = fmaxf(mx.z, y.z); mx.w = fmaxf(mx.w, y.w);
  }
  psum4[rg * 16 + c4] = s;
  pmax4[rg * 16 + c4] = mx;
  __syncthreads();
  if (tid < 16) {
    float4 S = psum4[tid], M = pmax4[tid];
    for (int j = 1; j < 16; ++j) {
      float4 p = psum4[j * 16 + tid], q = pmax4[j * 16 + tid];
      S.x += p.x; S.y += p.y; S.z += p.z; S.w += p.w;
      M.x = fmaxf(M.x, q.x); M.y = fmaxf(M.y, q.y);
      M.z = fmaxf(M.z, q.z); M.w = fmaxf(M.w, q.w);
    }
    const float inv = 1.0f / NPG;
    ((float4*)emb)[tid] = make_float4(S.x * inv, S.y * inv, S.z * inv, S.w * inv);
    ((float4*)emb)[16 + tid] = M;
  }
  __syncthreads();
  if (tid < 32) {
    float acc = 0.0f;
#pragma unroll
    for (int k = 0; k < 128; ++k) acc += emb[k] * Wf1[k * 32 + tid];
    z[g * 32 + tid] = acc;
  }
}

// single block: BNf stats over z -> coeffs -> relu -> FC2 -> out
__global__ __launch_bounds__(256) void k_final(const float* __restrict__ z,
                                               const float* __restrict__ gf,
                                               const float* __restrict__ bef,
                                               const float* __restrict__ Wf2,
                                               const float* __restrict__ bf2,
                                               float* __restrict__ out, int G) {
  __shared__ float ss[32], qs[32], af[32], cf[32];
  __shared__ float w2s[64], b2s[2];
  int tid = threadIdx.x;
  if (tid < 32) { ss[tid] = 0.0f; qs[tid] = 0.0f; }
  if (tid < 64) w2s[tid] = Wf2[tid];
  if (tid < 2) b2s[tid] = bf2[tid];
  __syncthreads();
  const float4* z4 = (const float4*)z;
  int n4 = G * 8;
  float4 s = {0.f, 0.f, 0.f, 0.f}, q = {0.f, 0.f, 0.f, 0.f};
  for (int i = tid; i < n4; i += 256) {
    float4 v = z4[i];
    s.x += v.x; s.y += v.y; s.z += v.z; s.w += v.w;
    q.x += v.x * v.x; q.y += v.y * v.y; q.z += v.z * v.z; q.w += v.w * v.w;
  }
  int cg = (tid & 7) * 4;
  atomicAdd(&ss[cg + 0], s.x); atomicAdd(&ss[cg + 1], s.y);
  atomicAdd(&ss[cg + 2], s.z); atomicAdd(&ss[cg + 3], s.w);
  atomicAdd(&qs[cg + 0], q.x); atomicAdd(&qs[cg + 1], q.y);
  atomicAdd(&qs[cg + 2], q.z); atomicAdd(&qs[cg + 3], q.w);
  __syncthreads();
  if (tid < 32) {
    float invG = 1.0f / G;
    float m = ss[tid] * invG;
    float v = qs[tid] * invG - m * m;
    float a = gf[tid] * rsqrtf(v + EPS);
    af[tid] = a;
    cf[tid] = bef[tid] - m * a;
  }
  __syncthreads();
  for (int g = tid; g < G; g += 256) {
    float o0 = b2s[0], o1 = b2s[1];
    const float4* zr = z4 + g * 8;
#pragma unroll
    for (int kc = 0; kc < 8; ++kc) {
      float4 v = zr[kc];
      int j = 4 * kc;
      float y;
      y = fmaxf(0.f, af[j + 0] * v.x + cf[j + 0]);
      o0 += y * w2s[2 * (j + 0)]; o1 += y * w2s[2 * (j + 0) + 1];
      y = fmaxf(0.f, af[j + 1] * v.y + cf[j + 1]);
      o0 += y * w2s[2 * (j + 1)]; o1 += y * w2s[2 * (j + 1) + 1];
      y = fmaxf(0.f, af[j + 2] * v.z + cf[j + 2]);
      o0 += y * w2s[2 * (j + 2)]; o1 += y * w2s[2 * (j + 2) + 1];
      y = fmaxf(0.f, af[j + 3] * v.w + cf[j + 3]);
      o0 += y * w2s[2 * (j + 3)]; o1 += y * w2s[2 * (j + 3) + 1];
    }
    out[g * 2] = o0;
    out[g * 2 + 1] = o1;
  }
}

extern "C" void kernel_launch(void* const* d_in, const int* in_sizes, int n_in,
                              void* d_out, int out_size, void* d_ws, size_t ws_size,
                              hipStream_t stream) {
  const float* x   = (const float*)d_in[0];
  const int*   ei  = (const int*)d_in[1];
  const float* ew  = (const float*)d_in[2];
  // d_in[3]=batch (implicit), d_in[5]=b1, d_in[9]=b2, d_in[13]=bf1 cancel
  // under training-mode BN and are unused.
  const float* W1  = (const float*)d_in[4];
  const float* g1  = (const float*)d_in[6];
  const float* be1 = (const float*)d_in[7];
  const float* W2  = (const float*)d_in[8];
  const float* g2  = (const float*)d_in[10];
  const float* be2 = (const float*)d_in[11];
  const float* Wf1 = (const float*)d_in[12];
  const float* gf  = (const float*)d_in[14];
  const float* bef = (const float*)d_in[15];
  const float* Wf2 = (const float*)d_in[16];
  const float* bf2 = (const float*)d_in[17];

  int N = in_sizes[3];   // 118784
  int E = in_sizes[2];   // 3801088
  int G = N / NPG;       // 1024

  float* ws    = (float*)d_ws;
  float* stats = ws;         // 256 floats (s1,q1,s2,q2)
  float* dinv  = ws + 256;   // N
  float* h1    = dinv + N;
  float* h2    = h1 + (size_t)N * HID;
  float* z     = h2 + (size_t)N * HID2;
  float* out   = (float*)d_out;
  float invN   = 1.0f / (float)N;

  hipMemsetAsync(stats, 0, 256 * sizeof(float), stream);
  k_conv1<<<G, 512, 0, stream>>>(x, ei, ew, W1, h1, dinv, stats, N, E);
  k_conv2<<<G, 512, 0, stream>>>(h1, ei, ew, W2, g1, be1, stats, dinv, h2,
                                 stats + 64, invN, N, E);
  k_pool<<<G, 256, 0, stream>>>(h2, g2, be2, stats + 64, Wf1, z, invN, N);
  k_final<<<1, 256, 0, stream>>>(z, gf, bef, Wf2, bf2, out, G);
}

// Round 9
// 153.525 us; speedup vs baseline: 12.8136x; 1.3736x over previous
//
#include <hip/hip_runtime.h>

#define NPG 116          // nodes per graph
#define EPG (NPG * 32)   // 3712 edges per graph
#define HID 32
#define HID2 64
#define EPS 1e-5f

#define WFS 132          // Wf fp32 row stride (mod 32 = 4 -> 2-way banks, free)
#define AS 136           // bf16 tile k-stride (shorts): 272B, 16B-aligned
#define YSS 40           // ysb/W2T k-stride (shorts): 80B, 16B-aligned
#define WBI 58           // packed ints per W row (116 shorts)
#define WBTOT (NPG * WBI)        // 6728 ints per graph
#define HPG (NPG * HID2)         // 7424 floats: per-graph Wb/h2 overlay region

using bf16x8 = __attribute__((ext_vector_type(8))) short;
using f32x4  = __attribute__((ext_vector_type(4))) float;

__device__ __forceinline__ unsigned short f2bf(float f) {
  union { float f; unsigned int i; } cv;
  cv.f = f;
  unsigned int x = cv.i;
  x += 0x7fff + ((x >> 16) & 1);   // RNE
  return (unsigned short)(x >> 16);
}

#define MFMA16(a, b, c) __builtin_amdgcn_mfma_f32_16x16x32_bf16((a), (b), (c), 0, 0, 0)

// ---------------------------------------------------------------------------
// ws layout (floats):
//   [0,256)   stats: s1[32] q1[32] s2[64] q2[64]  (memset 0 each launch)
//   [256,+N)  dinv
//   [+32N)    h1
//   [+G*HPG)  buf: per graph, packed bf16 W (6728 ints) written by conv1,
//             read by conv2 phase1, then OVERWRITTEN by h2 (7424 f) phase3.
//   [+32G)    z
// ---------------------------------------------------------------------------

// conv1: one edge pass (deg + raw-W atomics) || gemm1 MFMA (x from global) ->
// L1T = bf16(dinv*L1), pack W -> buf -> h1 = dinv*(W @ L1') + BN1 stats.
// 1024 thr = 16 waves (4/SIMD).  LDS ~80 KB.
__global__ __launch_bounds__(1024) void k_conv1(const float* __restrict__ x,
                                                const int* __restrict__ ei,
                                                const float* __restrict__ ew,
                                                const float* __restrict__ W1,
                                                float* __restrict__ h1,
                                                float* __restrict__ dinvg,
                                                float* __restrict__ stats,
                                                float* __restrict__ buf,
                                                int N, int E) {
  __shared__ __align__(16) float Wf[NPG * WFS];     // 61.2 KB raw W (fp32)
  __shared__ __align__(16) short W1T[HID * AS];     // 8.7 KB
  __shared__ __align__(16) short L1T[HID * AS];     // 8.7 KB
  __shared__ float degs[NPG];
  __shared__ float ss[HID], qs[HID];
  const int g = blockIdx.x, tid = threadIdx.x;
  const int nb = g * NPG, e0 = g * EPG;
  const int* rowp = ei;
  const int* colp = ei + E;
  const int l = tid & 63, w = tid >> 6;   // 16 waves
  const int rf = l & 15, kg = l >> 4;

  // P0: zero Wf/L1T (pads must be 0), stage W1T (global->LDS, pads 0)
  for (int i = tid; i < NPG; i += 1024) degs[i] = 1.0f;  // self-loop weight
  if (tid < HID) { ss[tid] = 0.0f; qs[tid] = 0.0f; }
  { float4* p = (float4*)Wf;
    for (int i = tid; i < NPG * WFS / 4; i += 1024) p[i] = make_float4(0,0,0,0); }
  { int* p = (int*)L1T;
    for (int i = tid; i < HID * AS / 2; i += 1024) p[i] = 0; }
  { int* p = (int*)W1T;
    for (int i = tid; i < HID * AS / 2; i += 1024) p[i] = 0; }
  __syncthreads();
  for (int i = tid; i < NPG * HID; i += 1024) {   // W1T[c][k] = W1[k][c]
    int k = i >> 5, c = i & 31;
    W1T[c * AS + k] = (short)f2bf(W1[i]);
  }
  // (W1T race-free vs gemm1: barrier below)
  __syncthreads();

  // P1: single edge pass (deg + W atomics) || gemm1 MFMA (x streamed global)
  for (int e = tid; e < EPG; e += 1024) {
    int eg = e0 + e;
    int s = rowp[eg] - nb, d = colp[eg] - nb;
    float wv = ew[eg];
    atomicAdd(&degs[d], wv);
    atomicAdd(&Wf[d * WFS + s], wv);
  }
  if (tid < NPG) atomicAdd(&Wf[tid * WFS + tid], 1.0f);   // self loop

  const int mt = w >> 1, nt = w & 1;   // wave -> gemm1 tile
  const int rl = mt * 16 + rf;
  f32x4 acc1 = {0.f, 0.f, 0.f, 0.f};
#pragma unroll
  for (int kk = 0; kk < 4; ++kk) {
    bf16x8 a;
    if (rl < NPG) {
      const float* xr = x + (size_t)(nb + rl) * NPG;
      if (kk < 3) {
        const float4* xp = (const float4*)(xr + kk * 32 + kg * 8);
        float4 v0 = xp[0], v1 = xp[1];
        a[0] = (short)f2bf(v0.x); a[1] = (short)f2bf(v0.y);
        a[2] = (short)f2bf(v0.z); a[3] = (short)f2bf(v0.w);
        a[4] = (short)f2bf(v1.x); a[5] = (short)f2bf(v1.y);
        a[6] = (short)f2bf(v1.z); a[7] = (short)f2bf(v1.w);
      } else {
        const int k0 = 96 + kg * 8;
#pragma unroll
        for (int j = 0; j < 8; ++j) {
          int k = k0 + j;
          a[j] = (k < NPG) ? (short)f2bf(xr[k]) : (short)0;
        }
      }
    } else {
#pragma unroll
      for (int j = 0; j < 8; ++j) a[j] = 0;
    }
    bf16x8 b = *(const bf16x8*)&W1T[(nt * 16 + rf) * AS + kk * 32 + kg * 8];
    acc1 = MFMA16(a, b, acc1);
  }
  __syncthreads();   // degs + Wf final

  // P2: L1T = bf16(dinv[row]*acc), dinvg write, pack W -> buf (bf16)
#pragma unroll
  for (int i = 0; i < 4; ++i) {
    int row = mt * 16 + kg * 4 + i;
    if (row < NPG)
      L1T[(nt * 16 + rf) * AS + row] = (short)f2bf(rsqrtf(degs[row]) * acc1[i]);
  }
  if (tid < NPG) dinvg[nb + tid] = rsqrtf(degs[tid]);
  {
    int* wbg = (int*)(buf + (size_t)g * HPG);
    for (int idx = tid; idx < WBTOT; idx += 1024) {
      int r = idx / WBI, jj = idx - r * WBI;
      float2 v = *(const float2*)&Wf[r * WFS + 2 * jj];
      wbg[idx] = (unsigned)f2bf(v.x) | ((unsigned)f2bf(v.y) << 16);
    }
  }
  __syncthreads();   // L1T ready

  // P3: h1 = dinv[row] * (W @ L1')  -- a-frags converted from Wf in-register
  {
    f32x4 acc = {0.f, 0.f, 0.f, 0.f};
#pragma unroll
    for (int kk = 0; kk < 4; ++kk) {
      bf16x8 a;
      if (rl < NPG) {
        const float4* wp = (const float4*)&Wf[rl * WFS + kk * 32 + kg * 8];
        float4 v0 = wp[0], v1 = wp[1];
        a[0] = (short)f2bf(v0.x); a[1] = (short)f2bf(v0.y);
        a[2] = (short)f2bf(v0.z); a[3] = (short)f2bf(v0.w);
        a[4] = (short)f2bf(v1.x); a[5] = (short)f2bf(v1.y);
        a[6] = (short)f2bf(v1.z); a[7] = (short)f2bf(v1.w);
      } else {
#pragma unroll
        for (int j = 0; j < 8; ++j) a[j] = 0;
      }
      bf16x8 b = *(const bf16x8*)&L1T[(nt * 16 + rf) * AS + kk * 32 + kg * 8];
      acc = MFMA16(a, b, acc);
    }
    const int col = nt * 16 + rf;
    float s_ = 0.f, q_ = 0.f;
#pragma unroll
    for (int i = 0; i < 4; ++i) {
      int row = mt * 16 + kg * 4 + i;
      if (row < NPG) {
        float v = rsqrtf(degs[row]) * acc[i];
        h1[(size_t)(nb + row) * HID + col] = v;
        s_ += v; q_ += v * v;
      }
    }
    atomicAdd(&ss[col], s_);
    atomicAdd(&qs[col], q_);
  }
  __syncthreads();
  if (tid < HID) {
    atomicAdd(&stats[tid], ss[tid]);
    atomicAdd(&stats[32 + tid], qs[tid]);
  }
}

// conv2: Wb memcpy from buf (no edges, no atomics) -> ys'=dinv*relu(BN1(h1))
// bf16 -> L2T = ys'@W2 (MFMA) -> h2 = dinv*(W @ L2') + BN2 stats.
// 1024 thr.  LDS ~68 KB.
__global__ __launch_bounds__(1024) void k_conv2(const float* __restrict__ h1,
                                                const float* __restrict__ W2,
                                                const float* __restrict__ g1,
                                                const float* __restrict__ be1,
                                                const float* __restrict__ stats,
                                                const float* __restrict__ dinvg,
                                                float* __restrict__ buf,
                                                float* __restrict__ stats2,
                                                float invN, int N) {
  __shared__ __align__(16) short Ab[128 * AS];     // 34.8 KB bf16 W
  __shared__ __align__(16) short ysb[128 * YSS];   // 10.2 KB
  __shared__ __align__(16) short W2T[HID2 * YSS];  // 5.1 KB
  __shared__ __align__(16) short L2T[HID2 * AS];   // 17.4 KB
  __shared__ float dv[NPG];
  __shared__ float ss[HID2], qs[HID2];
  __shared__ float a1s[HID], c1s[HID];
  const int g = blockIdx.x, tid = threadIdx.x;
  const int nb = g * NPG;
  const int l = tid & 63, w = tid >> 6;
  const int rf = l & 15, kg = l >> 4;
  float* bufg = buf + (size_t)g * HPG;

  // P0a: BN1 coefs, zero Ab/L2T, stage W2T, load dinv
  if (tid < HID) {
    float m = stats[tid] * invN;
    float v = stats[32 + tid] * invN - m * m;
    float a = g1[tid] * rsqrtf(v + EPS);
    a1s[tid] = a;
    c1s[tid] = be1[tid] - m * a;
  }
  if (tid < HID2) { ss[tid] = 0.0f; qs[tid] = 0.0f; }
  { int* p = (int*)Ab;
    for (int i = tid; i < 128 * AS / 2; i += 1024) p[i] = 0; }
  { int* p = (int*)L2T;
    for (int i = tid; i < HID2 * AS / 2; i += 1024) p[i] = 0; }
  for (int i = tid; i < HID * HID2; i += 1024) {   // W2T[c][k] = W2[k][c]
    int k = i >> 6, c = i & 63;
    W2T[c * YSS + k] = (short)f2bf(W2[i]);
  }
  for (int i = tid; i < NPG; i += 1024) dv[i] = dinvg[nb + i];
  __syncthreads();

  // P0b: ysb = bf16(dv[r]*relu(a1*h1+c1)); Ab copy-in from buf
  {
    const float4* hg = (const float4*)(h1 + (size_t)nb * HID);
    for (int i = tid; i < NPG * 8; i += 1024) {
      int r = i >> 3, kc = i & 7, k0 = kc * 4;
      float4 hv = hg[i];
      float dr = dv[r];
      float y0 = dr * fmaxf(0.f, a1s[k0 + 0] * hv.x + c1s[k0 + 0]);
      float y1 = dr * fmaxf(0.f, a1s[k0 + 1] * hv.y + c1s[k0 + 1]);
      float y2 = dr * fmaxf(0.f, a1s[k0 + 2] * hv.z + c1s[k0 + 2]);
      float y3 = dr * fmaxf(0.f, a1s[k0 + 3] * hv.w + c1s[k0 + 3]);
      unsigned int* yp = (unsigned int*)&ysb[r * YSS + k0];
      yp[0] = (unsigned)f2bf(y0) | ((unsigned)f2bf(y1) << 16);
      yp[1] = (unsigned)f2bf(y2) | ((unsigned)f2bf(y3) << 16);
    }
    const int* wbg = (const int*)bufg;
    int* ab = (int*)Ab;
    for (int idx = tid; idx < WBTOT; idx += 1024) {
      int r = idx / WBI, jj = idx - r * WBI;
      ab[r * (AS / 2) + jj] = wbg[idx];
    }
  }
  __syncthreads();

  // P1: gemm2: L2T = ys'@W2  (32 tiles / 16 waves = 2 per wave; K=32)
#pragma unroll
  for (int half = 0; half < 2; ++half) {
    const int t = w + 16 * half;
    const int mt = t >> 2, nt = t & 3;
    bf16x8 a = *(const bf16x8*)&ysb[(mt * 16 + rf) * YSS + kg * 8];
    bf16x8 b = *(const bf16x8*)&W2T[(nt * 16 + rf) * YSS + kg * 8];
    f32x4 acc = {0.f, 0.f, 0.f, 0.f};
    acc = MFMA16(a, b, acc);
    const int col = nt * 16 + rf;
#pragma unroll
    for (int i = 0; i < 4; ++i) {
      int row = mt * 16 + kg * 4 + i;
      if (row < NPG) L2T[col * AS + row] = (short)f2bf(acc[i]);
    }
  }
  __syncthreads();   // L2T ready

  // P2: h2 = dv[row] * (W @ L2'): wave -> (mt = w>>1, 2 n-tiles), 4 k-steps
  {
    const int mt = w >> 1, ntp = (w & 1) * 2;
    f32x4 acc[2] = {{0.f,0.f,0.f,0.f},{0.f,0.f,0.f,0.f}};
#pragma unroll
    for (int kk = 0; kk < 4; ++kk) {
      bf16x8 a = *(const bf16x8*)&Ab[(mt * 16 + rf) * AS + kk * 32 + kg * 8];
#pragma unroll
      for (int u = 0; u < 2; ++u) {
        bf16x8 b = *(const bf16x8*)&L2T[((ntp + u) * 16 + rf) * AS + kk * 32 + kg * 8];
        acc[u] = MFMA16(a, b, acc[u]);
      }
    }
#pragma unroll
    for (int u = 0; u < 2; ++u) {
      const int col = (ntp + u) * 16 + rf;
      float s_ = 0.f, q_ = 0.f;
#pragma unroll
      for (int i = 0; i < 4; ++i) {
        int row = mt * 16 + kg * 4 + i;
        if (row < NPG) {
          float v = dv[row] * acc[u][i];
          bufg[row * HID2 + col] = v;     // h2 overlays Wb (already consumed)
          s_ += v; q_ += v * v;
        }
      }
      atomicAdd(&ss[col], s_);
      atomicAdd(&qs[col], q_);
    }
  }
  __syncthreads();
  if (tid < HID2) {
    atomicAdd(&stats2[tid], ss[tid]);
    atomicAdd(&stats2[64 + tid], qs[tid]);
  }
}

// per-graph BN2 coefs + relu, mean/max pool, FC1 -> z
__global__ __launch_bounds__(256) void k_pool(const float* __restrict__ buf,
                                              const float* __restrict__ g2,
                                              const float* __restrict__ be2,
                                              const float* __restrict__ stats2,
                                              const float* __restrict__ Wf1,
                                              float* __restrict__ z,
                                              float invN, int N) {
  __shared__ float4 psum4[256], pmax4[256];
  __shared__ __align__(16) float emb[128];
  __shared__ __align__(16) float a2s[HID2], c2s[HID2];
  int g = blockIdx.x, tid = threadIdx.x;
  if (tid < HID2) {
    float m = stats2[tid] * invN;
    float v = stats2[64 + tid] * invN - m * m;
    float a = g2[tid] * rsqrtf(v + EPS);
    a2s[tid] = a;
    c2s[tid] = be2[tid] - m * a;
  }
  __syncthreads();
  int c4 = tid & 15, rg = tid >> 4;
  float4 av = ((const float4*)a2s)[c4], bv = ((const float4*)c2s)[c4];
  const float4* h4 = (const float4*)(buf + (size_t)g * HPG);
  float4 s = {0.f, 0.f, 0.f, 0.f};
  float4 mx = {-1e30f, -1e30f, -1e30f, -1e30f};
  for (int n = rg; n < NPG; n += 16) {
    float4 v = h4[n * 16 + c4];
    float4 y;
    y.x = fmaxf(0.f, av.x * v.x + bv.x);
    y.y = fmaxf(0.f, av.y * v.y + bv.y);
    y.z = fmaxf(0.f, av.z * v.z + bv.z);
    y.w = fmaxf(0.f, av.w * v.w + bv.w);
    s.x += y.x; s.y += y.y; s.z += y.z; s.w += y.w;
    mx.x = fmaxf(mx.x, y.x); mx.y = fmaxf(mx.y, y.y);
    mx.z = fmaxf(mx.z, y.z); mx.w = fmaxf(mx.w, y.w);
  }
  psum4[rg * 16 + c4] = s;
  pmax4[rg * 16 + c4] = mx;
  __syncthreads();
  if (tid < 16) {
    float4 S = psum4[tid], M = pmax4[tid];
    for (int j = 1; j < 16; ++j) {
      float4 p = psum4[j * 16 + tid], q = pmax4[j * 16 + tid];
      S.x += p.x; S.y += p.y; S.z += p.z; S.w += p.w;
      M.x = fmaxf(M.x, q.x); M.y = fmaxf(M.y, q.y);
      M.z = fmaxf(M.z, q.z); M.w = fmaxf(M.w, q.w);
    }
    const float inv = 1.0f / NPG;
    ((float4*)emb)[tid] = make_float4(S.x * inv, S.y * inv, S.z * inv, S.w * inv);
    ((float4*)emb)[16 + tid] = M;
  }
  __syncthreads();
  if (tid < 32) {
    float acc = 0.0f;
#pragma unroll
    for (int k = 0; k < 128; ++k) acc += emb[k] * Wf1[k * 32 + tid];
    z[g * 32 + tid] = acc;
  }
}

// single block: BNf stats over z -> coeffs -> relu -> FC2 -> out
__global__ __launch_bounds__(256) void k_final(const float* __restrict__ z,
                                               const float* __restrict__ gf,
                                               const float* __restrict__ bef,
                                               const float* __restrict__ Wf2,
                                               const float* __restrict__ bf2,
                                               float* __restrict__ out, int G) {
  __shared__ float ss[32], qs[32], af[32], cf[32];
  __shared__ float w2s[64], b2s[2];
  int tid = threadIdx.x;
  if (tid < 32) { ss[tid] = 0.0f; qs[tid] = 0.0f; }
  if (tid < 64) w2s[tid] = Wf2[tid];
  if (tid < 2) b2s[tid] = bf2[tid];
  __syncthreads();
  const float4* z4 = (const float4*)z;
  int n4 = G * 8;
  float4 s = {0.f, 0.f, 0.f, 0.f}, q = {0.f, 0.f, 0.f, 0.f};
  for (int i = tid; i < n4; i += 256) {
    float4 v = z4[i];
    s.x += v.x; s.y += v.y; s.z += v.z; s.w += v.w;
    q.x += v.x * v.x; q.y += v.y * v.y; q.z += v.z * v.z; q.w += v.w * v.w;
  }
  int cg = (tid & 7) * 4;
  atomicAdd(&ss[cg + 0], s.x); atomicAdd(&ss[cg + 1], s.y);
  atomicAdd(&ss[cg + 2], s.z); atomicAdd(&ss[cg + 3], s.w);
  atomicAdd(&qs[cg + 0], q.x); atomicAdd(&qs[cg + 1], q.y);
  atomicAdd(&qs[cg + 2], q.z); atomicAdd(&qs[cg + 3], q.w);
  __syncthreads();
  if (tid < 32) {
    float invG = 1.0f / G;
    float m = ss[tid] * invG;
    float v = qs[tid] * invG - m * m;
    float a = gf[tid] * rsqrtf(v + EPS);
    af[tid] = a;
    cf[tid] = bef[tid] - m * a;
  }
  __syncthreads();
  for (int g = tid; g < G; g += 256) {
    float o0 = b2s[0], o1 = b2s[1];
    const float4* zr = z4 + g * 8;
#pragma unroll
    for (int kc = 0; kc < 8; ++kc) {
      float4 v = zr[kc];
      int j = 4 * kc;
      float y;
      y = fmaxf(0.f, af[j + 0] * v.x + cf[j + 0]);
      o0 += y * w2s[2 * (j + 0)]; o1 += y * w2s[2 * (j + 0) + 1];
      y = fmaxf(0.f, af[j + 1] * v.y + cf[j + 1]);
      o0 += y * w2s[2 * (j + 1)]; o1 += y * w2s[2 * (j + 1) + 1];
      y = fmaxf(0.f, af[j + 2] * v.z + cf[j + 2]);
      o0 += y * w2s[2 * (j + 2)]; o1 += y * w2s[2 * (j + 2) + 1];
      y = fmaxf(0.f, af[j + 3] * v.w + cf[j + 3]);
      o0 += y * w2s[2 * (j + 3)]; o1 += y * w2s[2 * (j + 3) + 1];
    }
    out[g * 2] = o0;
    out[g * 2 + 1] = o1;
  }
}

extern "C" void kernel_launch(void* const* d_in, const int* in_sizes, int n_in,
                              void* d_out, int out_size, void* d_ws, size_t ws_size,
                              hipStream_t stream) {
  const float* x   = (const float*)d_in[0];
  const int*   ei  = (const int*)d_in[1];
  const float* ew  = (const float*)d_in[2];
  // d_in[3]=batch (implicit), d_in[5]=b1, d_in[9]=b2, d_in[13]=bf1 cancel
  // under training-mode BN and are unused.
  const float* W1  = (const float*)d_in[4];
  const float* g1  = (const float*)d_in[6];
  const float* be1 = (const float*)d_in[7];
  const float* W2  = (const float*)d_in[8];
  const float* g2  = (const float*)d_in[10];
  const float* be2 = (const float*)d_in[11];
  const float* Wf1 = (const float*)d_in[12];
  const float* gf  = (const float*)d_in[14];
  const float* bef = (const float*)d_in[15];
  const float* Wf2 = (const float*)d_in[16];
  const float* bf2 = (const float*)d_in[17];

  int N = in_sizes[3];   // 118784
  int E = in_sizes[2];   // 3801088
  int G = N / NPG;       // 1024

  float* ws    = (float*)d_ws;
  float* stats = ws;                       // 256
  float* dinv  = ws + 256;                 // N
  float* h1    = dinv + N;                 // 32N
  float* buf   = h1 + (size_t)N * HID;     // G*HPG (Wb then h2)
  float* z     = buf + (size_t)G * HPG;    // 32G
  float* out   = (float*)d_out;
  float invN   = 1.0f / (float)N;

  hipMemsetAsync(stats, 0, 256 * sizeof(float), stream);
  k_conv1<<<G, 1024, 0, stream>>>(x, ei, ew, W1, h1, dinv, stats, buf, N, E);
  k_conv2<<<G, 1024, 0, stream>>>(h1, W2, g1, be1, stats, dinv, buf,
                                  stats + 64, invN, N);
  k_pool<<<G, 256, 0, stream>>>(buf, g2, be2, stats + 64, Wf1, z, invN, N);
  k_final<<<1, 256, 0, stream>>>(z, gf, bef, Wf2, bf2, out, G);
}